// Round 2
// baseline (1757.264 us; speedup 1.0000x reference)
//
#include <hip/hip_runtime.h>
#include <hip/hip_bf16.h>

// Problem constants (match reference)
constexpr int B_ = 4, S_ = 2048, H_ = 4096;
constexpr int E_ = 64, K_ = 4, T_ = 4;
constexpr int D_ = 100, KI_ = 2048;
constexpr float EPS_ = 1e-6f;
constexpr float NEG_ = -1e9f;

typedef __bf16 bf16x4 __attribute__((ext_vector_type(4)));
typedef __bf16 bf16x8 __attribute__((ext_vector_type(8)));
typedef float  f32x4  __attribute__((ext_vector_type(4)));

// global_load_lds: LDS dest is wave-uniform base + lane*16 (linear); global
// source address is per-lane. Size must be the literal 16.
#define GLL(gp, ldsbyte)                                                        \
    __builtin_amdgcn_global_load_lds(                                           \
        (__attribute__((address_space(1))) void*)(uintptr_t)(gp),               \
        (__attribute__((address_space(3))) void*)(uintptr_t)((char*)smem + (ldsbyte)), \
        16, 0, 0)

// ---------------------------------------------------------------------------
// K1: RMSNorm fused with bf16 hi/lo split:  a_hi + a_lo ~= hs (err ~2^-17)
//     hs f32 is never materialized; all consumers use hi(+lo).
// ---------------------------------------------------------------------------
__global__ __launch_bounds__(256) void k_rmsnorm(const float* __restrict__ x,
                                                 const float* __restrict__ w,
                                                 __bf16* __restrict__ a_hi,
                                                 __bf16* __restrict__ a_lo) {
    const int row = blockIdx.x;
    const int t = threadIdx.x;
    const float4* xr = reinterpret_cast<const float4*>(x + (size_t)row * H_);
    const float4* wr = reinterpret_cast<const float4*>(w);

    float4 v[4];
    float ss = 0.f;
#pragma unroll
    for (int i = 0; i < 4; ++i) {
        v[i] = xr[t + 256 * i];
        ss += v[i].x * v[i].x + v[i].y * v[i].y + v[i].z * v[i].z + v[i].w * v[i].w;
    }
    __shared__ float red[4];
#pragma unroll
    for (int off = 32; off; off >>= 1) ss += __shfl_down(ss, off);
    if ((t & 63) == 0) red[t >> 6] = ss;
    __syncthreads();
    if (t == 0) {
        float s = red[0] + red[1] + red[2] + red[3];
        red[0] = rsqrtf(s / (float)H_ + EPS_);
    }
    __syncthreads();
    const float scale = red[0];
#pragma unroll
    for (int i = 0; i < 4; ++i) {
        float4 wv = wr[t + 256 * i];
        float e[4] = {v[i].x * scale * wv.x, v[i].y * scale * wv.y,
                      v[i].z * scale * wv.z, v[i].w * scale * wv.w};
        bf16x4 hv, lv;
#pragma unroll
        for (int c = 0; c < 4; ++c) {
            __bf16 h = (__bf16)e[c];
            hv[c] = h;
            lv[c] = (__bf16)(e[c] - (float)h);
        }
        const size_t o = (size_t)row * H_ + 4 * (t + 256 * i);
        *reinterpret_cast<bf16x4*>(a_hi + o) = hv;
        *reinterpret_cast<bf16x4*>(a_lo + o) = lv;
    }
}

// ---------------------------------------------------------------------------
// K2: transpose + split W1 = mlp_w[0:H,:]  ->  bt_hi/bt_lo [N=H][K=H] bf16
//     (GEMM B-operand staged as rows of K, matching A staging exactly)
// ---------------------------------------------------------------------------
__global__ __launch_bounds__(256) void k_wsplit(const float* __restrict__ w1,
                                                __bf16* __restrict__ bt_hi,
                                                __bf16* __restrict__ bt_lo) {
    __shared__ float sT[64][68];
    const int k0 = blockIdx.x * 64;
    const int n0 = blockIdx.y * 64;
    const int t = threadIdx.x;

#pragma unroll
    for (int q = 0; q < 4; ++q) {
        const int r = (t >> 4) + q * 16;
        const int c = (t & 15) * 4;
        float4 v = *reinterpret_cast<const float4*>(&w1[(size_t)(k0 + r) * H_ + n0 + c]);
        *reinterpret_cast<float4*>(&sT[r][c]) = v;
    }
    __syncthreads();
#pragma unroll
    for (int p = 0; p < 2; ++p) {
        const int n = (t >> 3) + p * 32;
        const int kc = (t & 7) * 8;
        bf16x8 hv, lv;
#pragma unroll
        for (int j = 0; j < 8; ++j) {
            float x = sT[kc + j][n];
            __bf16 h = (__bf16)x;
            hv[j] = h;
            lv[j] = (__bf16)(x - (float)h);
        }
        const size_t o = (size_t)(n0 + n) * H_ + k0 + kc;
        *reinterpret_cast<bf16x8*>(bt_hi + o) = hv;
        *reinterpret_cast<bf16x8*>(bt_lo + o) = lv;
    }
}

// ---------------------------------------------------------------------------
// K3: per-entity mean of gathered subtoken hidden states (hi+lo reconstruct)
// ---------------------------------------------------------------------------
__global__ __launch_bounds__(256) void k_bvec(const __bf16* __restrict__ a_hi,
                                              const __bf16* __restrict__ a_lo,
                                              const int* __restrict__ wst,
                                              float* __restrict__ bvec) {
    const int be = blockIdx.x;
    const int b = be / E_;
    const int t = threadIdx.x;

    int pos[T_];
    int cnt = 0;
#pragma unroll
    for (int j = 0; j < T_; ++j) {
        int p = wst[be * T_ + j];
        if (p >= 0) cnt++; else p = -1;
        pos[j] = p;
    }
    const float inv = 1.f / (float)(cnt > 0 ? cnt : 1);

    float acc[16] = {};
#pragma unroll
    for (int j = 0; j < T_; ++j) {
        if (pos[j] >= 0) {
            const size_t ro = ((size_t)b * S_ + pos[j]) * H_ + t * 16;
            const bf16x8* rh = reinterpret_cast<const bf16x8*>(a_hi + ro);
            const bf16x8* rl = reinterpret_cast<const bf16x8*>(a_lo + ro);
#pragma unroll
            for (int c2 = 0; c2 < 2; ++c2) {
                bf16x8 h = rh[c2], l = rl[c2];
#pragma unroll
                for (int e = 0; e < 8; ++e)
                    acc[c2 * 8 + e] += (float)h[e] + (float)l[e];
            }
        }
    }
    float4* dst = reinterpret_cast<float4*>(bvec + (size_t)be * H_ + t * 16);
#pragma unroll
    for (int c = 0; c < 4; ++c) {
        float4 r = {acc[4 * c] * inv, acc[4 * c + 1] * inv,
                    acc[4 * c + 2] * inv, acc[4 * c + 3] * inv};
        dst[c] = r;
    }
}

// ---------------------------------------------------------------------------
// K4: gather concept embeddings + sentinel  ent_ori [B*E, 5, D]
// ---------------------------------------------------------------------------
__global__ __launch_bounds__(256) void k_entori(const int* __restrict__ we,
                                                const float* __restrict__ cemb,
                                                const float* __restrict__ sent,
                                                float* __restrict__ ent) {
    const int be = blockIdx.x;
    for (int idx = threadIdx.x; idx < 5 * D_; idx += 256) {
        const int k = idx / D_, d = idx % D_;
        float v;
        if (k < K_) {
            int c = we[be * K_ + k];
            if (c < 0) c = 0;
            v = cemb[(size_t)c * D_ + d];
        } else {
            v = sent[d];
        }
        ent[(size_t)be * (5 * D_) + idx] = v;
    }
}

// ---------------------------------------------------------------------------
// K5: h1 = silu(ent @ gate_w) * (ent @ up_w)   [1280, KI], K=D=100 (f32 VALU)
// ---------------------------------------------------------------------------
__global__ __launch_bounds__(256) void k_gateup(const float* __restrict__ ent,
                                                const float* __restrict__ gw,
                                                const float* __restrict__ uw,
                                                float* __restrict__ h1) {
    __shared__ float sA[64][D_];
    __shared__ float sG[D_][64];
    const int n0 = blockIdx.x * 64;
    const int m0 = blockIdx.y * 64;
    const int t = threadIdx.x;
    const int tx = t & 15, ty = t >> 4;

    for (int idx = t; idx < 64 * D_; idx += 256) {
        int m = idx / D_, d = idx % D_;
        sA[m][d] = ent[(size_t)(m0 + m) * D_ + d];
    }
    for (int idx = t; idx < D_ * 64; idx += 256) {
        int d = idx / 64, n = idx % 64;
        sG[d][n] = gw[(size_t)d * KI_ + n0 + n];
    }
    __syncthreads();

    float g[4][4] = {}, u[4][4] = {};
    for (int d = 0; d < D_; ++d) {
        float a[4], bg[4];
        float4 bu = *reinterpret_cast<const float4*>(&uw[(size_t)d * KI_ + n0 + tx * 4]);
        float bub[4] = {bu.x, bu.y, bu.z, bu.w};
#pragma unroll
        for (int i = 0; i < 4; ++i) a[i] = sA[ty * 4 + i][d];
#pragma unroll
        for (int j = 0; j < 4; ++j) bg[j] = sG[d][tx * 4 + j];
#pragma unroll
        for (int i = 0; i < 4; ++i)
#pragma unroll
            for (int j = 0; j < 4; ++j) {
                g[i][j] += a[i] * bg[j];
                u[i][j] += a[i] * bub[j];
            }
    }
#pragma unroll
    for (int i = 0; i < 4; ++i) {
        float4 r;
        float* rv = &r.x;
#pragma unroll
        for (int j = 0; j < 4; ++j) {
            float gv = g[i][j];
            rv[j] = (gv / (1.f + expf(-gv))) * u[i][j];
        }
        *reinterpret_cast<float4*>(&h1[(size_t)(m0 + ty * 4 + i) * KI_ + n0 + tx * 4]) = r;
    }
}

// ---------------------------------------------------------------------------
// K6: bd[m, ki] = sum_h bvec[m,h] * down_w[ki,h]  (reassociated logits path)
// ---------------------------------------------------------------------------
__global__ __launch_bounds__(256) void k_bd(const float* __restrict__ bvec,
                                            const float* __restrict__ dw,
                                            float* __restrict__ bd) {
    __shared__ float sA[64][20];
    __shared__ float sB[64][20];
    const int n0 = blockIdx.x * 64;
    const int m0 = blockIdx.y * 64;
    const int t = threadIdx.x;
    const int tx = t & 15, ty = t >> 4;
    const int lr = t >> 2, lc = (t & 3) * 4;

    float acc[4][4] = {};
    for (int k0 = 0; k0 < H_; k0 += 16) {
        *reinterpret_cast<float4*>(&sA[lr][lc]) =
            *reinterpret_cast<const float4*>(&bvec[(size_t)(m0 + lr) * H_ + k0 + lc]);
        *reinterpret_cast<float4*>(&sB[lr][lc]) =
            *reinterpret_cast<const float4*>(&dw[(size_t)(n0 + lr) * H_ + k0 + lc]);
        __syncthreads();
#pragma unroll
        for (int kk = 0; kk < 16; ++kk) {
            float a[4], b[4];
#pragma unroll
            for (int i = 0; i < 4; ++i) a[i] = sA[ty * 4 + i][kk];
#pragma unroll
            for (int j = 0; j < 4; ++j) b[j] = sB[tx * 4 + j][kk];
#pragma unroll
            for (int i = 0; i < 4; ++i)
#pragma unroll
                for (int j = 0; j < 4; ++j) acc[i][j] += a[i] * b[j];
        }
        __syncthreads();
    }
#pragma unroll
    for (int i = 0; i < 4; ++i) {
        float4 r = {acc[i][0], acc[i][1], acc[i][2], acc[i][3]};
        *reinterpret_cast<float4*>(&bd[(size_t)(m0 + ty * 4 + i) * KI_ + n0 + tx * 4]) = r;
    }
}

// ---------------------------------------------------------------------------
// K7: logits = h1 . bd ; softmax(+mask) ; attn_out = attn @ ent_ori
// ---------------------------------------------------------------------------
__global__ __launch_bounds__(256) void k_attn(const float* __restrict__ h1,
                                              const float* __restrict__ bd,
                                              const float* __restrict__ ent,
                                              const int* __restrict__ we,
                                              float* __restrict__ attn_out) {
    __shared__ float sbd[KI_];
    __shared__ float red[4];
    __shared__ float sl[8];
    const int be = blockIdx.x;
    const int t = threadIdx.x;

    for (int i = t; i < KI_; i += 256) sbd[i] = bd[(size_t)be * KI_ + i];
    __syncthreads();

    for (int k = 0; k < 5; ++k) {
        const float* hrow = h1 + ((size_t)be * 5 + k) * KI_;
        float s = 0.f;
        for (int i = t; i < KI_; i += 256) s += hrow[i] * sbd[i];
#pragma unroll
        for (int off = 32; off; off >>= 1) s += __shfl_down(s, off);
        if ((t & 63) == 0) red[t >> 6] = s;
        __syncthreads();
        if (t == 0) sl[k] = red[0] + red[1] + red[2] + red[3];
        __syncthreads();
    }
    if (t == 0) {
        float lg[5];
#pragma unroll
        for (int k = 0; k < K_; ++k)
            lg[k] = sl[k] + (we[be * K_ + k] == -1 ? NEG_ : 0.f);
        lg[4] = sl[4];
        float mx = lg[0];
#pragma unroll
        for (int k = 1; k < 5; ++k) mx = fmaxf(mx, lg[k]);
        float sum = 0.f;
#pragma unroll
        for (int k = 0; k < 5; ++k) { lg[k] = expf(lg[k] - mx); sum += lg[k]; }
        float is = 1.f / sum;
#pragma unroll
        for (int k = 0; k < 5; ++k) sl[k] = lg[k] * is;
    }
    __syncthreads();
    if (t < D_) {
        float a = 0.f;
#pragma unroll
        for (int k = 0; k < 5; ++k) a += sl[k] * ent[((size_t)be * 5 + k) * D_ + t];
        attn_out[(size_t)be * D_ + t] = a;
    }
}

// ---------------------------------------------------------------------------
// K8: main GEMM  Y = hs @ W1  via bf16x3 MFMA  (M=8192, N=4096, K=4096)
//     m97 structure: 128x128 tile, BK=32, 4 waves (2x2, 64x64 each),
//     16x16x32 MFMA, global_load_lds dwordx4 staging, 2-barrier K-loop.
//     3 products per K-step: hi*hi + hi*lo + lo*hi (err ~2^-16 rel).
//     Layouts (m89/m92-verified): A-frag lane l: A[l&15][8*(l>>4)+j];
//     B-frag from B^T rows: B[8*(l>>4)+j][l&15]; C/D: col=l&15, row=(l>>4)*4+r.
// ---------------------------------------------------------------------------
__global__ __launch_bounds__(256) void k_mfma_gemm(const __bf16* __restrict__ Ahi,
                                                   const __bf16* __restrict__ Alo,
                                                   const __bf16* __restrict__ Bhi,
                                                   const __bf16* __restrict__ Blo,
                                                   float* __restrict__ C) {
    // LDS: 4 tiles of [128 rows][32 k] bf16 (8KB each): Ahi|Alo|Bhi|Blo
    __shared__ __align__(16) __bf16 smem[16384];
    const int t = threadIdx.x;
    const int lane = t & 63, wid = t >> 6;
    const int wr = wid >> 1, wc = wid & 1;

    // XCD-aware bijective swizzle (nwg = 2048, divisible by 8)
    const int bid = blockIdx.x;
    const int swz = (bid & 7) * 256 + (bid >> 3);
    const int mb = swz >> 5, nb = swz & 31;
    const size_t m0 = (size_t)mb * 128, n0 = (size_t)nb * 128;

    // staging geometry: chunk c -> row = c>>2, k-elem = (c&3)*8.
    // wave w covers chunks [w*128, w*128+128) via 2 issues of 64 lanes.
    const int c0 = wid * 128 + lane, c1 = c0 + 64;
    const size_t offA0 = ((size_t)(m0 + (c0 >> 2))) * H_ + (c0 & 3) * 8;
    const size_t offA1 = ((size_t)(m0 + (c1 >> 2))) * H_ + (c1 & 3) * 8;
    const size_t offB0 = ((size_t)(n0 + (c0 >> 2))) * H_ + (c0 & 3) * 8;
    const size_t offB1 = ((size_t)(n0 + (c1 >> 2))) * H_ + (c1 & 3) * 8;
    const unsigned ldsW = wid * 2048;   // bytes, wave region within a tile

    const int fr = lane & 15;           // fragment row within 16-group
    const int kq = (lane >> 4) * 8;     // fragment k-offset (elements)

    f32x4 acc[4][4] = {};

    for (int k0 = 0; k0 < H_; k0 += 32) {
        GLL(Ahi + offA0 + k0, 0 + ldsW);
        GLL(Ahi + offA1 + k0, 0 + ldsW + 1024);
        GLL(Alo + offA0 + k0, 8192 + ldsW);
        GLL(Alo + offA1 + k0, 8192 + ldsW + 1024);
        GLL(Bhi + offB0 + k0, 16384 + ldsW);
        GLL(Bhi + offB1 + k0, 16384 + ldsW + 1024);
        GLL(Blo + offB0 + k0, 24576 + ldsW);
        GLL(Blo + offB1 + k0, 24576 + ldsW + 1024);
        __syncthreads();   // compiler drains vmcnt(0) before s_barrier

        bf16x8 ahi[4], alo[4], bhi[4], blo[4];
#pragma unroll
        for (int i = 0; i < 4; ++i) {
            const int ar = (wr * 64 + i * 16 + fr) * 32 + kq;
            const int br = (wc * 64 + i * 16 + fr) * 32 + kq;
            ahi[i] = *reinterpret_cast<const bf16x8*>(smem + ar);
            alo[i] = *reinterpret_cast<const bf16x8*>(smem + 4096 + ar);
            bhi[i] = *reinterpret_cast<const bf16x8*>(smem + 8192 + br);
            blo[i] = *reinterpret_cast<const bf16x8*>(smem + 12288 + br);
        }
#pragma unroll
        for (int i = 0; i < 4; ++i)
#pragma unroll
            for (int j = 0; j < 4; ++j) {
                acc[i][j] = __builtin_amdgcn_mfma_f32_16x16x32_bf16(ahi[i], bhi[j], acc[i][j], 0, 0, 0);
                acc[i][j] = __builtin_amdgcn_mfma_f32_16x16x32_bf16(ahi[i], blo[j], acc[i][j], 0, 0, 0);
                acc[i][j] = __builtin_amdgcn_mfma_f32_16x16x32_bf16(alo[i], bhi[j], acc[i][j], 0, 0, 0);
            }
        __syncthreads();
    }

    const int cr = (lane >> 4) * 4;
    const int cc = lane & 15;
#pragma unroll
    for (int i = 0; i < 4; ++i) {
#pragma unroll
        for (int j = 0; j < 4; ++j) {
            const size_t row = m0 + wr * 64 + i * 16 + cr;
            const size_t col = n0 + wc * 64 + j * 16 + cc;
#pragma unroll
            for (int r = 0; r < 4; ++r)
                C[(row + r) * H_ + col] = acc[i][j][r];
        }
    }
}

// ---------------------------------------------------------------------------
// K9: sparse scatter-add  Y[b,pos,:] += attn_out[b,e,:] @ W2  (W2 = mlp_w[H:,:])
// ---------------------------------------------------------------------------
__global__ __launch_bounds__(256) void k_scatter(const float* __restrict__ attn_out,
                                                 const float* __restrict__ mlpw,
                                                 const int* __restrict__ wst,
                                                 float* __restrict__ Y) {
    __shared__ float sa[D_];
    const int be = blockIdx.x;
    const int b = be / E_;
    const int t = threadIdx.x;
    if (t < D_) sa[t] = attn_out[(size_t)be * D_ + t];
    __syncthreads();

    int pos[T_];
    int np = 0;
#pragma unroll
    for (int j = 0; j < T_; ++j) {
        int p = wst[be * T_ + j];
        if (p >= 0 && p < S_) pos[np++] = p;
    }
    if (np == 0) return;

    const float* W2 = mlpw + (size_t)H_ * H_;
#pragma unroll
    for (int i = 0; i < 4; ++i) {
        const int h4 = t + 256 * i;
        float4 c = make_float4(0.f, 0.f, 0.f, 0.f);
        for (int d = 0; d < D_; ++d) {
            float4 w = *reinterpret_cast<const float4*>(&W2[(size_t)d * H_ + 4 * h4]);
            float av = sa[d];
            c.x += av * w.x; c.y += av * w.y; c.z += av * w.z; c.w += av * w.w;
        }
        for (int j = 0; j < np; ++j) {
            float4* yp = reinterpret_cast<float4*>(&Y[((size_t)b * S_ + pos[j]) * H_ + 4 * h4]);
            float4 y = *yp;
            y.x += c.x; y.y += c.y; y.z += c.z; y.w += c.w;
            *yp = y;
        }
    }
}

// ---------------------------------------------------------------------------
// K10: out = silu(Y + bias) * alpha + residual   (bias fused here, pre-silu)
// ---------------------------------------------------------------------------
__global__ __launch_bounds__(256) void k_final(float* __restrict__ Y,
                                               const float* __restrict__ resid,
                                               const float* __restrict__ alpha,
                                               const float* __restrict__ bias) {
    const float a = alpha[0];
    const float4* rr = reinterpret_cast<const float4*>(resid);
    const float4* bb = reinterpret_cast<const float4*>(bias);
    float4* yy = reinterpret_cast<float4*>(Y);
    const size_t base = (size_t)blockIdx.x * 1024 + threadIdx.x;
#pragma unroll
    for (int i = 0; i < 4; ++i) {
        size_t idx = base + 256 * i;
        float4 y = yy[idx];
        float4 r = rr[idx];
        float4 bv = bb[(threadIdx.x + 256 * i) & 1023];   // idx % (H/4)
        float4 o;
        float vx = y.x + bv.x, vy = y.y + bv.y, vz = y.z + bv.z, vw = y.w + bv.w;
        o.x = (vx / (1.f + expf(-vx))) * a + r.x;
        o.y = (vy / (1.f + expf(-vy))) * a + r.y;
        o.z = (vz / (1.f + expf(-vz))) * a + r.z;
        o.w = (vw / (1.f + expf(-vw))) * a + r.w;
        yy[idx] = o;
    }
}

// ---------------------------------------------------------------------------
extern "C" void kernel_launch(void* const* d_in, const int* in_sizes, int n_in,
                              void* d_out, int out_size, void* d_ws, size_t ws_size,
                              hipStream_t stream) {
    const float* hidden = (const float*)d_in[0];
    const int*   we     = (const int*)d_in[1];
    const int*   wst    = (const int*)d_in[2];
    const float* cemb   = (const float*)d_in[3];
    const float* sent   = (const float*)d_in[4];
    const float* lnw    = (const float*)d_in[5];
    const float* gw     = (const float*)d_in[6];
    const float* uw     = (const float*)d_in[7];
    const float* dw     = (const float*)d_in[8];
    const float* mlpw   = (const float*)d_in[9];
    const float* mlpb   = (const float*)d_in[10];
    const float* alpha  = (const float*)d_in[11];
    float* out = (float*)d_out;

    // workspace layout (bytes); total ~218.8 MB
    char* w = (char*)d_ws;
    __bf16* a_hi  = (__bf16*)(w);                    //  67,108,864  [M][K] bf16
    __bf16* a_lo  = (__bf16*)(w + 67108864);         //  67,108,864
    __bf16* bt_hi = (__bf16*)(w + 134217728);        //  33,554,432  [N][K] bf16
    __bf16* bt_lo = (__bf16*)(w + 167772160);        //  33,554,432
    float*  bvec  = (float*)(w + 201326592);         //   4,194,304  [B*E][H]
    float*  ent   = (float*)(w + 205520896);         //     512,000  [B*E][5][D]
    float*  h1    = (float*)(w + 206032896);         //  10,485,760  [B*E*5][KI]
    float*  bd    = (float*)(w + 216518656);         //   2,097,152  [B*E][KI]
    float*  attn  = (float*)(w + 218615808);         //     102,400  [B*E][D]

    k_rmsnorm<<<B_ * S_, 256, 0, stream>>>(hidden, lnw, a_hi, a_lo);
    k_wsplit<<<dim3(H_ / 64, H_ / 64), 256, 0, stream>>>(mlpw, bt_hi, bt_lo);
    k_entori<<<B_ * E_, 256, 0, stream>>>(we, cemb, sent, ent);
    k_bvec<<<B_ * E_, 256, 0, stream>>>(a_hi, a_lo, wst, bvec);
    k_gateup<<<dim3(KI_ / 64, (B_ * E_ * 5) / 64), 256, 0, stream>>>(ent, gw, uw, h1);
    k_bd<<<dim3(KI_ / 64, (B_ * E_) / 64), 256, 0, stream>>>(bvec, dw, bd);
    k_attn<<<B_ * E_, 256, 0, stream>>>(h1, bd, ent, we, attn);
    k_mfma_gemm<<<(H_ / 128) * ((B_ * S_) / 128), 256, 0, stream>>>(a_hi, a_lo, bt_hi, bt_lo, out);
    k_scatter<<<B_ * E_, 256, 0, stream>>>(attn, mlpw, wst, out);
    k_final<<<(size_t)(B_ * S_ * H_) / 4096, 256, 0, stream>>>(out, hidden, alpha, mlpb);
}

// Round 5
// 1059.897 us; speedup vs baseline: 1.6580x; 1.6580x over previous
//
#include <hip/hip_runtime.h>
#include <hip/hip_bf16.h>

// Problem constants (match reference)
constexpr int B_ = 4, S_ = 2048, H_ = 4096;
constexpr int E_ = 64, K_ = 4, T_ = 4;
constexpr int D_ = 100, KI_ = 2048;
constexpr float EPS_ = 1e-6f;
constexpr float NEG_ = -1e9f;

typedef _Float16 f16x8 __attribute__((ext_vector_type(8)));
typedef _Float16 f16x4 __attribute__((ext_vector_type(4)));
typedef float    f32x4 __attribute__((ext_vector_type(4)));

// global_load_lds: LDS dest is wave-uniform base + lane*16 (linear); global
// source address is per-lane. Size must be the literal 16.
#define GLL(gp, ldsbyte)                                                        \
    __builtin_amdgcn_global_load_lds(                                           \
        (__attribute__((address_space(1))) void*)(uintptr_t)(gp),               \
        (__attribute__((address_space(3))) void*)(uintptr_t)((char*)smem + (ldsbyte)), \
        16, 0, 0)

// ---------------------------------------------------------------------------
// K1: RMSNorm -> fp16   a16 = fp16(w * x * rsqrt(mean(x^2)+eps))
// ---------------------------------------------------------------------------
__global__ __launch_bounds__(256) void k_rmsnorm(const float* __restrict__ x,
                                                 const float* __restrict__ w,
                                                 _Float16* __restrict__ a16) {
    const int row = blockIdx.x;
    const int t = threadIdx.x;
    const float4* xr = reinterpret_cast<const float4*>(x + (size_t)row * H_);
    const float4* wr = reinterpret_cast<const float4*>(w);

    float4 v[4];
    float ss = 0.f;
#pragma unroll
    for (int i = 0; i < 4; ++i) {
        v[i] = xr[t + 256 * i];
        ss += v[i].x * v[i].x + v[i].y * v[i].y + v[i].z * v[i].z + v[i].w * v[i].w;
    }
    __shared__ float red[4];
#pragma unroll
    for (int off = 32; off; off >>= 1) ss += __shfl_down(ss, off);
    if ((t & 63) == 0) red[t >> 6] = ss;
    __syncthreads();
    if (t == 0) {
        float s = red[0] + red[1] + red[2] + red[3];
        red[0] = rsqrtf(s / (float)H_ + EPS_);
    }
    __syncthreads();
    const float scale = red[0];
#pragma unroll
    for (int i = 0; i < 4; ++i) {
        float4 wv = wr[t + 256 * i];
        f16x4 hv;
        hv[0] = (_Float16)(v[i].x * scale * wv.x);
        hv[1] = (_Float16)(v[i].y * scale * wv.y);
        hv[2] = (_Float16)(v[i].z * scale * wv.z);
        hv[3] = (_Float16)(v[i].w * scale * wv.w);
        *reinterpret_cast<f16x4*>(a16 + (size_t)row * H_ + 4 * (t + 256 * i)) = hv;
    }
}

// ---------------------------------------------------------------------------
// K2: transpose W1 = mlp_w[0:H,:]  ->  bt16 [N=H][K=H] fp16 (B^T for GEMM)
// ---------------------------------------------------------------------------
__global__ __launch_bounds__(256) void k_wsplit(const float* __restrict__ w1,
                                                _Float16* __restrict__ bt16) {
    __shared__ float sT[64][68];
    const int k0 = blockIdx.x * 64;
    const int n0 = blockIdx.y * 64;
    const int t = threadIdx.x;

#pragma unroll
    for (int q = 0; q < 4; ++q) {
        const int r = (t >> 4) + q * 16;
        const int c = (t & 15) * 4;
        float4 v = *reinterpret_cast<const float4*>(&w1[(size_t)(k0 + r) * H_ + n0 + c]);
        *reinterpret_cast<float4*>(&sT[r][c]) = v;
    }
    __syncthreads();
#pragma unroll
    for (int p = 0; p < 2; ++p) {
        const int n = (t >> 3) + p * 32;
        const int kc = (t & 7) * 8;
        f16x8 hv;
#pragma unroll
        for (int j = 0; j < 8; ++j) hv[j] = (_Float16)sT[kc + j][n];
        *reinterpret_cast<f16x8*>(bt16 + (size_t)(n0 + n) * H_ + k0 + kc) = hv;
    }
}

// ---------------------------------------------------------------------------
// K3: gather concept embeddings + sentinel; also init inv map to -1
// ---------------------------------------------------------------------------
__global__ __launch_bounds__(256) void k_entori(const int* __restrict__ we,
                                                const float* __restrict__ cemb,
                                                const float* __restrict__ sent,
                                                float* __restrict__ ent,
                                                int* __restrict__ inv) {
    const int be = blockIdx.x;
    const int t = threadIdx.x;
    if (t < 32) inv[be * 32 + t] = -1;     // B*S = 256*32
    for (int idx = t; idx < 5 * D_; idx += 256) {
        const int k = idx / D_, d = idx % D_;
        float v;
        if (k < K_) {
            int c = we[be * K_ + k];
            if (c < 0) c = 0;
            v = cemb[(size_t)c * D_ + d];
        } else {
            v = sent[d];
        }
        ent[(size_t)be * (5 * D_) + idx] = v;
    }
}

// K3b: inv[b*S + pos] = be for each subtoken position (positions unique/sample)
__global__ __launch_bounds__(256) void k_invset(const int* __restrict__ wst,
                                                int* __restrict__ inv) {
    const int be = threadIdx.x;
    if (be < B_ * E_) {
        const int b = be / E_;
#pragma unroll
        for (int j = 0; j < T_; ++j) {
            int p = wst[be * T_ + j];
            if (p >= 0 && p < S_) inv[b * S_ + p] = be;
        }
    }
}

// ---------------------------------------------------------------------------
// K4: per-entity mean of gathered subtoken hidden states (fp16 -> f32 acc)
// ---------------------------------------------------------------------------
__global__ __launch_bounds__(256) void k_bvec(const _Float16* __restrict__ a16,
                                              const int* __restrict__ wst,
                                              float* __restrict__ bvec) {
    const int be = blockIdx.x;
    const int b = be / E_;
    const int t = threadIdx.x;

    int pos[T_];
    int cnt = 0;
#pragma unroll
    for (int j = 0; j < T_; ++j) {
        int p = wst[be * T_ + j];
        if (p >= 0) cnt++; else p = -1;
        pos[j] = p;
    }
    const float inv = 1.f / (float)(cnt > 0 ? cnt : 1);

    float acc[16] = {};
#pragma unroll
    for (int j = 0; j < T_; ++j) {
        if (pos[j] >= 0) {
            const f16x8* rh = reinterpret_cast<const f16x8*>(
                a16 + ((size_t)b * S_ + pos[j]) * H_ + t * 16);
#pragma unroll
            for (int c2 = 0; c2 < 2; ++c2) {
                f16x8 h = rh[c2];
#pragma unroll
                for (int e = 0; e < 8; ++e) acc[c2 * 8 + e] += (float)h[e];
            }
        }
    }
    float4* dst = reinterpret_cast<float4*>(bvec + (size_t)be * H_ + t * 16);
#pragma unroll
    for (int c = 0; c < 4; ++c) {
        float4 r = {acc[4 * c] * inv, acc[4 * c + 1] * inv,
                    acc[4 * c + 2] * inv, acc[4 * c + 3] * inv};
        dst[c] = r;
    }
}

// ---------------------------------------------------------------------------
// K5: h1 = silu(ent @ gate_w) * (ent @ up_w)   [1280, KI], K=D=100 (f32 VALU)
// ---------------------------------------------------------------------------
__global__ __launch_bounds__(256) void k_gateup(const float* __restrict__ ent,
                                                const float* __restrict__ gw,
                                                const float* __restrict__ uw,
                                                float* __restrict__ h1) {
    __shared__ float sA[64][D_];
    __shared__ float sG[D_][64];
    const int n0 = blockIdx.x * 64;
    const int m0 = blockIdx.y * 64;
    const int t = threadIdx.x;
    const int tx = t & 15, ty = t >> 4;

    for (int idx = t; idx < 64 * D_; idx += 256) {
        int m = idx / D_, d = idx % D_;
        sA[m][d] = ent[(size_t)(m0 + m) * D_ + d];
    }
    for (int idx = t; idx < D_ * 64; idx += 256) {
        int d = idx / 64, n = idx % 64;
        sG[d][n] = gw[(size_t)d * KI_ + n0 + n];
    }
    __syncthreads();

    float g[4][4] = {}, u[4][4] = {};
    for (int d = 0; d < D_; ++d) {
        float a[4], bg[4];
        float4 bu = *reinterpret_cast<const float4*>(&uw[(size_t)d * KI_ + n0 + tx * 4]);
        float bub[4] = {bu.x, bu.y, bu.z, bu.w};
#pragma unroll
        for (int i = 0; i < 4; ++i) a[i] = sA[ty * 4 + i][d];
#pragma unroll
        for (int j = 0; j < 4; ++j) bg[j] = sG[d][tx * 4 + j];
#pragma unroll
        for (int i = 0; i < 4; ++i)
#pragma unroll
            for (int j = 0; j < 4; ++j) {
                g[i][j] += a[i] * bg[j];
                u[i][j] += a[i] * bub[j];
            }
    }
#pragma unroll
    for (int i = 0; i < 4; ++i) {
        float4 r;
        float* rv = &r.x;
#pragma unroll
        for (int j = 0; j < 4; ++j) {
            float gv = g[i][j];
            rv[j] = (gv / (1.f + expf(-gv))) * u[i][j];
        }
        *reinterpret_cast<float4*>(&h1[(size_t)(m0 + ty * 4 + i) * KI_ + n0 + tx * 4]) = r;
    }
}

// ---------------------------------------------------------------------------
// K6: split-K bd partials: bdp[z][m][ki] = sum_{h in chunk z} bvec[m,h]*dw[ki,h]
// ---------------------------------------------------------------------------
__global__ __launch_bounds__(256) void k_bd(const float* __restrict__ bvec,
                                            const float* __restrict__ dw,
                                            float* __restrict__ bdp) {
    __shared__ float sA[64][20];
    __shared__ float sB[64][20];
    const int n0 = blockIdx.x * 64;
    const int m0 = blockIdx.y * 64;
    const int z = blockIdx.z;
    const int t = threadIdx.x;
    const int tx = t & 15, ty = t >> 4;
    const int lr = t >> 2, lc = (t & 3) * 4;

    float acc[4][4] = {};
    for (int k0 = z * 512; k0 < (z + 1) * 512; k0 += 16) {
        *reinterpret_cast<float4*>(&sA[lr][lc]) =
            *reinterpret_cast<const float4*>(&bvec[(size_t)(m0 + lr) * H_ + k0 + lc]);
        *reinterpret_cast<float4*>(&sB[lr][lc]) =
            *reinterpret_cast<const float4*>(&dw[(size_t)(n0 + lr) * H_ + k0 + lc]);
        __syncthreads();
#pragma unroll
        for (int kk = 0; kk < 16; ++kk) {
            float a[4], b[4];
#pragma unroll
            for (int i = 0; i < 4; ++i) a[i] = sA[ty * 4 + i][kk];
#pragma unroll
            for (int j = 0; j < 4; ++j) b[j] = sB[tx * 4 + j][kk];
#pragma unroll
            for (int i = 0; i < 4; ++i)
#pragma unroll
                for (int j = 0; j < 4; ++j) acc[i][j] += a[i] * b[j];
        }
        __syncthreads();
    }
#pragma unroll
    for (int i = 0; i < 4; ++i) {
        float4 r = {acc[i][0], acc[i][1], acc[i][2], acc[i][3]};
        *reinterpret_cast<float4*>(
            &bdp[((size_t)z * 256 + m0 + ty * 4 + i) * KI_ + n0 + tx * 4]) = r;
    }
}

// ---------------------------------------------------------------------------
// K7: logits = h1 . (sum_z bdp) ; softmax(+mask) ; attn_out = attn @ ent_ori
// ---------------------------------------------------------------------------
__global__ __launch_bounds__(256) void k_attn(const float* __restrict__ h1,
                                              const float* __restrict__ bdp,
                                              const float* __restrict__ ent,
                                              const int* __restrict__ we,
                                              float* __restrict__ attn_out) {
    __shared__ float sbd[KI_];
    __shared__ float red[4];
    __shared__ float sl[8];
    const int be = blockIdx.x;
    const int t = threadIdx.x;

    for (int i = t; i < KI_; i += 256) {
        float s = 0.f;
#pragma unroll
        for (int z = 0; z < 8; ++z) s += bdp[((size_t)z * 256 + be) * KI_ + i];
        sbd[i] = s;
    }
    __syncthreads();

    for (int k = 0; k < 5; ++k) {
        const float* hrow = h1 + ((size_t)be * 5 + k) * KI_;
        float s = 0.f;
        for (int i = t; i < KI_; i += 256) s += hrow[i] * sbd[i];
#pragma unroll
        for (int off = 32; off; off >>= 1) s += __shfl_down(s, off);
        if ((t & 63) == 0) red[t >> 6] = s;
        __syncthreads();
        if (t == 0) sl[k] = red[0] + red[1] + red[2] + red[3];
        __syncthreads();
    }
    if (t == 0) {
        float lg[5];
#pragma unroll
        for (int k = 0; k < K_; ++k)
            lg[k] = sl[k] + (we[be * K_ + k] == -1 ? NEG_ : 0.f);
        lg[4] = sl[4];
        float mx = lg[0];
#pragma unroll
        for (int k = 1; k < 5; ++k) mx = fmaxf(mx, lg[k]);
        float sum = 0.f;
#pragma unroll
        for (int k = 0; k < 5; ++k) { lg[k] = expf(lg[k] - mx); sum += lg[k]; }
        float is = 1.f / sum;
#pragma unroll
        for (int k = 0; k < 5; ++k) sl[k] = lg[k] * is;
    }
    __syncthreads();
    if (t < D_) {
        float a = 0.f;
#pragma unroll
        for (int k = 0; k < 5; ++k) a += sl[k] * ent[((size_t)be * 5 + k) * D_ + t];
        attn_out[(size_t)be * D_ + t] = a;
    }
}

// ---------------------------------------------------------------------------
// K8: entw2[be][h] = attn_out[be] @ W2   (W2 = mlp_w[H:,:], D x H)
// ---------------------------------------------------------------------------
__global__ __launch_bounds__(256) void k_entw2(const float* __restrict__ attn_out,
                                               const float* __restrict__ mlpw,
                                               float* __restrict__ entw2) {
    __shared__ float sa[D_];
    const int be = blockIdx.x;
    const int t = threadIdx.x;
    if (t < D_) sa[t] = attn_out[(size_t)be * D_ + t];
    __syncthreads();

    const float* W2 = mlpw + (size_t)H_ * H_;
#pragma unroll
    for (int i = 0; i < 4; ++i) {
        const int h4 = t + 256 * i;          // float4 column index
        float4 c = make_float4(0.f, 0.f, 0.f, 0.f);
        for (int d = 0; d < D_; ++d) {
            float4 w = *reinterpret_cast<const float4*>(&W2[(size_t)d * H_ + 4 * h4]);
            float av = sa[d];
            c.x += av * w.x; c.y += av * w.y; c.z += av * w.z; c.w += av * w.w;
        }
        *reinterpret_cast<float4*>(&entw2[(size_t)be * H_ + 4 * h4]) = c;
    }
}

// ---------------------------------------------------------------------------
// K9: main GEMM  out = silu(A@W1^T + bias + entw2[inv]) * alpha + resid
//     fp16 MFMA, m97 structure: 128x128 tile, BK=32, 4 waves (2x2, 64x64),
//     16x16x32_f16, global_load_lds dwordx4 staging, 2-barrier K-loop.
//     LDS map (16KB): A tile [128][32] fp16 at byte 0, B tile at byte 8192.
// ---------------------------------------------------------------------------
__global__ __launch_bounds__(256) void k_mfma_gemm(const _Float16* __restrict__ A,
                                                   const _Float16* __restrict__ Bt,
                                                   const float* __restrict__ bias,
                                                   const float* __restrict__ resid,
                                                   const float* __restrict__ alphap,
                                                   const float* __restrict__ entw2,
                                                   const int* __restrict__ inv,
                                                   float* __restrict__ Out) {
    __shared__ __align__(16) _Float16 smem[8192];   // 16 KB total
    const int t = threadIdx.x;
    const int lane = t & 63, wid = t >> 6;
    const int wr = wid >> 1, wc = wid & 1;

    // XCD-aware bijective swizzle (nwg = 2048, divisible by 8)
    const int bid = blockIdx.x;
    const int swz = (bid & 7) * 256 + (bid >> 3);
    const int mb = swz >> 5, nb = swz & 31;
    const size_t m0 = (size_t)mb * 128, n0 = (size_t)nb * 128;

    // staging: chunk c -> row = c>>2, k-elem = (c&3)*8 (16B = 8 fp16)
    const int c0 = wid * 128 + lane, c1 = c0 + 64;
    const size_t offA0 = ((size_t)(m0 + (c0 >> 2))) * H_ + (c0 & 3) * 8;
    const size_t offA1 = ((size_t)(m0 + (c1 >> 2))) * H_ + (c1 & 3) * 8;
    const size_t offB0 = ((size_t)(n0 + (c0 >> 2))) * H_ + (c0 & 3) * 8;
    const size_t offB1 = ((size_t)(n0 + (c1 >> 2))) * H_ + (c1 & 3) * 8;
    const unsigned ldsW = wid * 2048;       // bytes, wave region within a tile

    const int fr = lane & 15;               // fragment row within 16-group
    const int kq = (lane >> 4) * 8;         // fragment k-offset (elements)

    f32x4 acc[4][4] = {};

    for (int k0 = 0; k0 < H_; k0 += 32) {
        GLL(A + offA0 + k0, ldsW);
        GLL(A + offA1 + k0, ldsW + 1024);
        GLL(Bt + offB0 + k0, 8192 + ldsW);          // B tile base = byte 8192
        GLL(Bt + offB1 + k0, 8192 + ldsW + 1024);
        __syncthreads();    // compiler drains vmcnt(0) before s_barrier

        f16x8 af[4], bf[4];
#pragma unroll
        for (int i = 0; i < 4; ++i) {
            af[i] = *reinterpret_cast<const f16x8*>(smem + (wr * 64 + i * 16 + fr) * 32 + kq);
            bf[i] = *reinterpret_cast<const f16x8*>(smem + 4096 + (wc * 64 + i * 16 + fr) * 32 + kq);
        }
#pragma unroll
        for (int i = 0; i < 4; ++i)
#pragma unroll
            for (int j = 0; j < 4; ++j)
                acc[i][j] = __builtin_amdgcn_mfma_f32_16x16x32_f16(af[i], bf[j], acc[i][j], 0, 0, 0);
        __syncthreads();
    }

    // fused epilogue: + bias + entity-scatter, silu, *alpha, +residual
    const float alpha = alphap[0];
    const int cr = (lane >> 4) * 4;
    const int cc = lane & 15;
#pragma unroll
    for (int i = 0; i < 4; ++i) {
        const int rowbase = (int)m0 + wr * 64 + i * 16 + cr;
        int bes[4];
#pragma unroll
        for (int r = 0; r < 4; ++r) bes[r] = inv[rowbase + r];
#pragma unroll
        for (int j = 0; j < 4; ++j) {
            const int col = (int)n0 + wc * 64 + j * 16 + cc;
            const float bv = bias[col];
#pragma unroll
            for (int r = 0; r < 4; ++r) {
                float v = acc[i][j][r] + bv;
                if (bes[r] >= 0) v += entw2[(size_t)bes[r] * H_ + col];
                const size_t o = (size_t)(rowbase + r) * H_ + col;
                Out[o] = (v / (1.f + expf(-v))) * alpha + resid[o];
            }
        }
    }
}

// ---------------------------------------------------------------------------
extern "C" void kernel_launch(void* const* d_in, const int* in_sizes, int n_in,
                              void* d_out, int out_size, void* d_ws, size_t ws_size,
                              hipStream_t stream) {
    const float* hidden = (const float*)d_in[0];
    const int*   we     = (const int*)d_in[1];
    const int*   wst    = (const int*)d_in[2];
    const float* cemb   = (const float*)d_in[3];
    const float* sent   = (const float*)d_in[4];
    const float* lnw    = (const float*)d_in[5];
    const float* gw     = (const float*)d_in[6];
    const float* uw     = (const float*)d_in[7];
    const float* dw     = (const float*)d_in[8];
    const float* mlpw   = (const float*)d_in[9];
    const float* mlpb   = (const float*)d_in[10];
    const float* alpha  = (const float*)d_in[11];
    float* out = (float*)d_out;

    // workspace layout (bytes), total ~137 MB
    char* w = (char*)d_ws;
    _Float16* a16   = (_Float16*)(w);                  //  67,108,864  [M][K]
    _Float16* bt16  = (_Float16*)(w + 67108864);       //  33,554,432  [N][K]
    float*    bvec  = (float*)(w + 100663296);         //   4,194,304
    float*    ent   = (float*)(w + 104857600);         //     512,000
    float*    h1    = (float*)(w + 105369600);         //  10,485,760
    float*    bdp   = (float*)(w + 115855360);         //  16,777,216  [8][256][KI]
    float*    attn  = (float*)(w + 132632576);         //     102,400
    float*    entw2 = (float*)(w + 132734976);         //   4,194,304  [256][H]
    int*      inv   = (int*)(w + 136929280);           //      32,768  [B*S]

    k_rmsnorm<<<B_ * S_, 256, 0, stream>>>(hidden, lnw, a16);
    k_wsplit<<<dim3(H_ / 64, H_ / 64), 256, 0, stream>>>(mlpw, bt16);
    k_entori<<<B_ * E_, 256, 0, stream>>>(we, cemb, sent, ent, inv);
    k_invset<<<1, 256, 0, stream>>>(wst, inv);
    k_bvec<<<B_ * E_, 256, 0, stream>>>(a16, wst, bvec);
    k_gateup<<<dim3(KI_ / 64, (B_ * E_ * 5) / 64), 256, 0, stream>>>(ent, gw, uw, h1);
    k_bd<<<dim3(KI_ / 64, (B_ * E_) / 64, 8), 256, 0, stream>>>(bvec, dw, bdp);
    k_attn<<<B_ * E_, 256, 0, stream>>>(h1, bdp, ent, we, attn);
    k_entw2<<<B_ * E_, 256, 0, stream>>>(attn, mlpw, entw2);
    k_mfma_gemm<<<(H_ / 128) * ((B_ * S_) / 128), 256, 0, stream>>>(
        a16, bt16, mlpb, hidden, alpha, entw2, inv, out);
}

// Round 7
// 985.974 us; speedup vs baseline: 1.7823x; 1.0750x over previous
//
#include <hip/hip_runtime.h>
#include <hip/hip_bf16.h>

// Problem constants (match reference)
constexpr int B_ = 4, S_ = 2048, H_ = 4096;
constexpr int E_ = 64, K_ = 4, T_ = 4;
constexpr int D_ = 100, KI_ = 2048;
constexpr float EPS_ = 1e-6f;
constexpr float NEG_ = -1e9f;

typedef _Float16 f16x8 __attribute__((ext_vector_type(8)));
typedef _Float16 f16x4 __attribute__((ext_vector_type(4)));
typedef float    f32x4 __attribute__((ext_vector_type(4)));

// global_load_lds: LDS dest is wave-uniform base + lane*16 (linear); global
// source address is per-lane. Size must be the literal 16.
#define GLL(gp, ldsbyte)                                                        \
    __builtin_amdgcn_global_load_lds(                                           \
        (__attribute__((address_space(1))) void*)(uintptr_t)(gp),               \
        (__attribute__((address_space(3))) void*)(uintptr_t)((char*)smem + (ldsbyte)), \
        16, 0, 0)

// ---------------------------------------------------------------------------
// K1: RMSNorm -> fp16   a16 = fp16(w * x * rsqrt(mean(x^2)+eps))
// ---------------------------------------------------------------------------
__global__ __launch_bounds__(256) void k_rmsnorm(const float* __restrict__ x,
                                                 const float* __restrict__ w,
                                                 _Float16* __restrict__ a16) {
    const int row = blockIdx.x;
    const int t = threadIdx.x;
    const float4* xr = reinterpret_cast<const float4*>(x + (size_t)row * H_);
    const float4* wr = reinterpret_cast<const float4*>(w);

    float4 v[4];
    float ss = 0.f;
#pragma unroll
    for (int i = 0; i < 4; ++i) {
        v[i] = xr[t + 256 * i];
        ss += v[i].x * v[i].x + v[i].y * v[i].y + v[i].z * v[i].z + v[i].w * v[i].w;
    }
    __shared__ float red[4];
#pragma unroll
    for (int off = 32; off; off >>= 1) ss += __shfl_down(ss, off);
    if ((t & 63) == 0) red[t >> 6] = ss;
    __syncthreads();
    if (t == 0) {
        float s = red[0] + red[1] + red[2] + red[3];
        red[0] = rsqrtf(s / (float)H_ + EPS_);
    }
    __syncthreads();
    const float scale = red[0];
#pragma unroll
    for (int i = 0; i < 4; ++i) {
        float4 wv = wr[t + 256 * i];
        f16x4 hv;
        hv[0] = (_Float16)(v[i].x * scale * wv.x);
        hv[1] = (_Float16)(v[i].y * scale * wv.y);
        hv[2] = (_Float16)(v[i].z * scale * wv.z);
        hv[3] = (_Float16)(v[i].w * scale * wv.w);
        *reinterpret_cast<f16x4*>(a16 + (size_t)row * H_ + 4 * (t + 256 * i)) = hv;
    }
}

// ---------------------------------------------------------------------------
// K2: transpose W1 = mlp_w[0:H,:]  ->  bt16 [N=H][K=H] fp16 (B^T for GEMM)
// ---------------------------------------------------------------------------
__global__ __launch_bounds__(256) void k_wsplit(const float* __restrict__ w1,
                                                _Float16* __restrict__ bt16) {
    __shared__ float sT[64][68];
    const int k0 = blockIdx.x * 64;
    const int n0 = blockIdx.y * 64;
    const int t = threadIdx.x;

#pragma unroll
    for (int q = 0; q < 4; ++q) {
        const int r = (t >> 4) + q * 16;
        const int c = (t & 15) * 4;
        float4 v = *reinterpret_cast<const float4*>(&w1[(size_t)(k0 + r) * H_ + n0 + c]);
        *reinterpret_cast<float4*>(&sT[r][c]) = v;
    }
    __syncthreads();
#pragma unroll
    for (int p = 0; p < 2; ++p) {
        const int n = (t >> 3) + p * 32;
        const int kc = (t & 7) * 8;
        f16x8 hv;
#pragma unroll
        for (int j = 0; j < 8; ++j) hv[j] = (_Float16)sT[kc + j][n];
        *reinterpret_cast<f16x8*>(bt16 + (size_t)(n0 + n) * H_ + k0 + kc) = hv;
    }
}

// ---------------------------------------------------------------------------
// K3: gather concept embeddings + sentinel; also init inv map to -1
// ---------------------------------------------------------------------------
__global__ __launch_bounds__(256) void k_entori(const int* __restrict__ we,
                                                const float* __restrict__ cemb,
                                                const float* __restrict__ sent,
                                                float* __restrict__ ent,
                                                int* __restrict__ inv) {
    const int be = blockIdx.x;
    const int t = threadIdx.x;
    if (t < 32) inv[be * 32 + t] = -1;     // B*S = 256*32
    for (int idx = t; idx < 5 * D_; idx += 256) {
        const int k = idx / D_, d = idx % D_;
        float v;
        if (k < K_) {
            int c = we[be * K_ + k];
            if (c < 0) c = 0;
            v = cemb[(size_t)c * D_ + d];
        } else {
            v = sent[d];
        }
        ent[(size_t)be * (5 * D_) + idx] = v;
    }
}

// K3b: inv[b*S + pos] = be for each subtoken position (positions unique/sample)
__global__ __launch_bounds__(256) void k_invset(const int* __restrict__ wst,
                                                int* __restrict__ inv) {
    const int be = threadIdx.x;
    if (be < B_ * E_) {
        const int b = be / E_;
#pragma unroll
        for (int j = 0; j < T_; ++j) {
            int p = wst[be * T_ + j];
            if (p >= 0 && p < S_) inv[b * S_ + p] = be;
        }
    }
}

// ---------------------------------------------------------------------------
// K4: per-entity mean of gathered subtoken hidden states (fp16 -> f32 acc)
// ---------------------------------------------------------------------------
__global__ __launch_bounds__(256) void k_bvec(const _Float16* __restrict__ a16,
                                              const int* __restrict__ wst,
                                              float* __restrict__ bvec) {
    const int be = blockIdx.x;
    const int b = be / E_;
    const int t = threadIdx.x;

    int pos[T_];
    int cnt = 0;
#pragma unroll
    for (int j = 0; j < T_; ++j) {
        int p = wst[be * T_ + j];
        if (p >= 0) cnt++; else p = -1;
        pos[j] = p;
    }
    const float inv = 1.f / (float)(cnt > 0 ? cnt : 1);

    float acc[16] = {};
#pragma unroll
    for (int j = 0; j < T_; ++j) {
        if (pos[j] >= 0) {
            const f16x8* rh = reinterpret_cast<const f16x8*>(
                a16 + ((size_t)b * S_ + pos[j]) * H_ + t * 16);
#pragma unroll
            for (int c2 = 0; c2 < 2; ++c2) {
                f16x8 h = rh[c2];
#pragma unroll
                for (int e = 0; e < 8; ++e) acc[c2 * 8 + e] += (float)h[e];
            }
        }
    }
    float4* dst = reinterpret_cast<float4*>(bvec + (size_t)be * H_ + t * 16);
#pragma unroll
    for (int c = 0; c < 4; ++c) {
        float4 r = {acc[4 * c] * inv, acc[4 * c + 1] * inv,
                    acc[4 * c + 2] * inv, acc[4 * c + 3] * inv};
        dst[c] = r;
    }
}

// ---------------------------------------------------------------------------
// K5: h1 = silu(ent @ gate_w) * (ent @ up_w)   [1280, KI], K=D=100 (f32 VALU)
//     micro-tile cols strided (tx + 16j): sG reads conflict-free (was 8-way)
// ---------------------------------------------------------------------------
__global__ __launch_bounds__(256) void k_gateup(const float* __restrict__ ent,
                                                const float* __restrict__ gw,
                                                const float* __restrict__ uw,
                                                float* __restrict__ h1) {
    __shared__ float sA[64][D_];
    __shared__ float sG[D_][64];
    const int n0 = blockIdx.x * 64;
    const int m0 = blockIdx.y * 64;
    const int t = threadIdx.x;
    const int tx = t & 15, ty = t >> 4;

    for (int idx = t; idx < 64 * D_; idx += 256) {
        int m = idx / D_, d = idx % D_;
        sA[m][d] = ent[(size_t)(m0 + m) * D_ + d];
    }
    for (int idx = t; idx < D_ * 64; idx += 256) {
        int d = idx / 64, n = idx % 64;
        sG[d][n] = gw[(size_t)d * KI_ + n0 + n];
    }
    __syncthreads();

    float g[4][4] = {}, u[4][4] = {};
    for (int d = 0; d < D_; ++d) {
        float a[4], bg[4], bub[4];
#pragma unroll
        for (int i = 0; i < 4; ++i) a[i] = sA[ty * 4 + i][d];
#pragma unroll
        for (int j = 0; j < 4; ++j) {
            bg[j] = sG[d][tx + 16 * j];
            bub[j] = uw[(size_t)d * KI_ + n0 + tx + 16 * j];
        }
#pragma unroll
        for (int i = 0; i < 4; ++i)
#pragma unroll
            for (int j = 0; j < 4; ++j) {
                g[i][j] += a[i] * bg[j];
                u[i][j] += a[i] * bub[j];
            }
    }
#pragma unroll
    for (int i = 0; i < 4; ++i)
#pragma unroll
        for (int j = 0; j < 4; ++j) {
            float gv = g[i][j];
            h1[(size_t)(m0 + ty * 4 + i) * KI_ + n0 + tx + 16 * j] =
                (gv / (1.f + expf(-gv))) * u[i][j];
        }
}

// ---------------------------------------------------------------------------
// K6: split-K bd partials: bdp[z][m][ki] = sum_{h in chunk z} bvec[m,h]*dw[ki,h]
//     micro-tile cols strided (tx + 16j): sB reads 2-way (free; was 8-way)
// ---------------------------------------------------------------------------
__global__ __launch_bounds__(256) void k_bd(const float* __restrict__ bvec,
                                            const float* __restrict__ dw,
                                            float* __restrict__ bdp) {
    __shared__ float sA[64][20];
    __shared__ float sB[64][20];
    const int n0 = blockIdx.x * 64;
    const int m0 = blockIdx.y * 64;
    const int z = blockIdx.z;
    const int t = threadIdx.x;
    const int tx = t & 15, ty = t >> 4;
    const int lr = t >> 2, lc = (t & 3) * 4;

    float acc[4][4] = {};
    for (int k0 = z * 512; k0 < (z + 1) * 512; k0 += 16) {
        *reinterpret_cast<float4*>(&sA[lr][lc]) =
            *reinterpret_cast<const float4*>(&bvec[(size_t)(m0 + lr) * H_ + k0 + lc]);
        *reinterpret_cast<float4*>(&sB[lr][lc]) =
            *reinterpret_cast<const float4*>(&dw[(size_t)(n0 + lr) * H_ + k0 + lc]);
        __syncthreads();
#pragma unroll
        for (int kk = 0; kk < 16; ++kk) {
            float a[4], b[4];
#pragma unroll
            for (int i = 0; i < 4; ++i) a[i] = sA[ty * 4 + i][kk];
#pragma unroll
            for (int j = 0; j < 4; ++j) b[j] = sB[tx + 16 * j][kk];
#pragma unroll
            for (int i = 0; i < 4; ++i)
#pragma unroll
                for (int j = 0; j < 4; ++j) acc[i][j] += a[i] * b[j];
        }
        __syncthreads();
    }
#pragma unroll
    for (int i = 0; i < 4; ++i)
#pragma unroll
        for (int j = 0; j < 4; ++j)
            bdp[((size_t)z * 256 + m0 + ty * 4 + i) * KI_ + n0 + tx + 16 * j] = acc[i][j];
}

// ---------------------------------------------------------------------------
// K7: logits = h1 . (sum_z bdp) ; softmax(+mask) ; attn_out = attn @ ent_ori
// ---------------------------------------------------------------------------
__global__ __launch_bounds__(256) void k_attn(const float* __restrict__ h1,
                                              const float* __restrict__ bdp,
                                              const float* __restrict__ ent,
                                              const int* __restrict__ we,
                                              float* __restrict__ attn_out) {
    __shared__ float sbd[KI_];
    __shared__ float red[4];
    __shared__ float sl[8];
    const int be = blockIdx.x;
    const int t = threadIdx.x;

    for (int i = t; i < KI_; i += 256) {
        float s = 0.f;
#pragma unroll
        for (int z = 0; z < 8; ++z) s += bdp[((size_t)z * 256 + be) * KI_ + i];
        sbd[i] = s;
    }
    __syncthreads();

    for (int k = 0; k < 5; ++k) {
        const float* hrow = h1 + ((size_t)be * 5 + k) * KI_;
        float s = 0.f;
        for (int i = t; i < KI_; i += 256) s += hrow[i] * sbd[i];
#pragma unroll
        for (int off = 32; off; off >>= 1) s += __shfl_down(s, off);
        if ((t & 63) == 0) red[t >> 6] = s;
        __syncthreads();
        if (t == 0) sl[k] = red[0] + red[1] + red[2] + red[3];
        __syncthreads();
    }
    if (t == 0) {
        float lg[5];
#pragma unroll
        for (int k = 0; k < K_; ++k)
            lg[k] = sl[k] + (we[be * K_ + k] == -1 ? NEG_ : 0.f);
        lg[4] = sl[4];
        float mx = lg[0];
#pragma unroll
        for (int k = 1; k < 5; ++k) mx = fmaxf(mx, lg[k]);
        float sum = 0.f;
#pragma unroll
        for (int k = 0; k < 5; ++k) { lg[k] = expf(lg[k] - mx); sum += lg[k]; }
        float is = 1.f / sum;
#pragma unroll
        for (int k = 0; k < 5; ++k) sl[k] = lg[k] * is;
    }
    __syncthreads();
    if (t < D_) {
        float a = 0.f;
#pragma unroll
        for (int k = 0; k < 5; ++k) a += sl[k] * ent[((size_t)be * 5 + k) * D_ + t];
        attn_out[(size_t)be * D_ + t] = a;
    }
}

// ---------------------------------------------------------------------------
// K8: entw2[be][h] = attn_out[be] @ W2   (W2 = mlp_w[H:,:], D x H)
// ---------------------------------------------------------------------------
__global__ __launch_bounds__(256) void k_entw2(const float* __restrict__ attn_out,
                                               const float* __restrict__ mlpw,
                                               float* __restrict__ entw2) {
    __shared__ float sa[D_];
    const int be = blockIdx.x;
    const int t = threadIdx.x;
    if (t < D_) sa[t] = attn_out[(size_t)be * D_ + t];
    __syncthreads();

    const float* W2 = mlpw + (size_t)H_ * H_;
#pragma unroll
    for (int i = 0; i < 4; ++i) {
        const int h4 = t + 256 * i;          // float4 column index
        float4 c = make_float4(0.f, 0.f, 0.f, 0.f);
        for (int d = 0; d < D_; ++d) {
            float4 w = *reinterpret_cast<const float4*>(&W2[(size_t)d * H_ + 4 * h4]);
            float av = sa[d];
            c.x += av * w.x; c.y += av * w.y; c.z += av * w.z; c.w += av * w.w;
        }
        *reinterpret_cast<float4*>(&entw2[(size_t)be * H_ + 4 * h4]) = c;
    }
}

// ---------------------------------------------------------------------------
// K9: main GEMM  out = silu(A@W1^T + bias + entw2[inv]) * alpha + resid
//     fp16 MFMA, 128x128 tile, BK=64, 4 waves (2x2, 64x64 each).
//     LDS 32KB: A [128 rows][64 k] at elem 0, B at elem 8192. Rows = 128 B.
//     Both-sides XOR swizzle (rule #21): LDS stays LINEAR for global_load_lds;
//     global source col-chunk q = slot ^ (row&7); read applies same XOR.
//     Kills the 16-way ds_read_b128 bank conflict of the linear layout.
// ---------------------------------------------------------------------------
__global__ __launch_bounds__(256) void k_mfma_gemm(const _Float16* __restrict__ A,
                                                   const _Float16* __restrict__ Bt,
                                                   const float* __restrict__ bias,
                                                   const float* __restrict__ resid,
                                                   const float* __restrict__ alphap,
                                                   const float* __restrict__ entw2,
                                                   const int* __restrict__ inv,
                                                   float* __restrict__ Out) {
    __shared__ __align__(16) _Float16 smem[16384];   // 32 KB
    const int t = threadIdx.x;
    const int lane = t & 63, wid = t >> 6;
    const int wr = wid >> 1, wc = wid & 1;

    // XCD-aware bijective swizzle (nwg = 2048, divisible by 8)
    const int bid = blockIdx.x;
    const int swz = (bid & 7) * 256 + (bid >> 3);
    const int mb = swz >> 5, nb = swz & 31;
    const size_t m0 = (size_t)mb * 128, n0 = (size_t)nb * 128;

    // staging: tile = 1024 chunks of 16B; chunk c -> row=c>>3, slot=c&7.
    // wave wid covers chunks [wid*256, wid*256+256) in 4 issues of 64 lanes.
    // LDS slot s of row r receives global col-chunk q = s ^ (r&7).
    int rowE[4], qE[4];
#pragma unroll
    for (int e = 0; e < 4; ++e) {
        const int c = wid * 256 + e * 64 + lane;
        rowE[e] = c >> 3;
        qE[e] = (c & 7) ^ (rowE[e] & 7);
    }
    const unsigned ldsA = wid * 4096;            // byte base of wave's A region
    const unsigned ldsB = 16384 + wid * 4096;    // byte base of wave's B region

    const int fr = lane & 15;            // fragment row within 16-group
    const int dq = lane >> 4;            // k-quarter (8 elems) within 32-k half

    f32x4 acc[4][4] = {};

    for (int k0 = 0; k0 < H_; k0 += 64) {
#pragma unroll
        for (int e = 0; e < 4; ++e) {
            GLL(A  + (size_t)(m0 + rowE[e]) * H_ + k0 + qE[e] * 8, ldsA + e * 1024);
            GLL(Bt + (size_t)(n0 + rowE[e]) * H_ + k0 + qE[e] * 8, ldsB + e * 1024);
        }
        __syncthreads();    // compiler drains vmcnt(0) before s_barrier

#pragma unroll
        for (int h = 0; h < 2; ++h) {
            f16x8 af[4], bf[4];
            const int slot8 = ((h * 4 + dq) ^ (fr & 7)) * 8;   // swizzled read
#pragma unroll
            for (int i = 0; i < 4; ++i) {
                const int ra = wr * 64 + i * 16 + fr;
                const int rb = wc * 64 + i * 16 + fr;
                af[i] = *reinterpret_cast<const f16x8*>(smem + ra * 64 + slot8);
                bf[i] = *reinterpret_cast<const f16x8*>(smem + 8192 + rb * 64 + slot8);
            }
#pragma unroll
            for (int i = 0; i < 4; ++i)
#pragma unroll
                for (int j = 0; j < 4; ++j)
                    acc[i][j] = __builtin_amdgcn_mfma_f32_16x16x32_f16(af[i], bf[j], acc[i][j], 0, 0, 0);
        }
        __syncthreads();
    }

    // fused epilogue: + bias + entity-scatter, silu, *alpha, +residual
    const float alpha = alphap[0];
    const int cr = (lane >> 4) * 4;
    const int cc = lane & 15;
#pragma unroll
    for (int i = 0; i < 4; ++i) {
        const int rowbase = (int)m0 + wr * 64 + i * 16 + cr;
        int bes[4];
#pragma unroll
        for (int r = 0; r < 4; ++r) bes[r] = inv[rowbase + r];
#pragma unroll
        for (int j = 0; j < 4; ++j) {
            const int col = (int)n0 + wc * 64 + j * 16 + cc;
            const float bv = bias[col];
#pragma unroll
            for (int r = 0; r < 4; ++r) {
                float v = acc[i][j][r] + bv;
                if (bes[r] >= 0) v += entw2[(size_t)bes[r] * H_ + col];
                const size_t o = (size_t)(rowbase + r) * H_ + col;
                Out[o] = (v / (1.f + expf(-v))) * alpha + resid[o];
            }
        }
    }
}

// ---------------------------------------------------------------------------
extern "C" void kernel_launch(void* const* d_in, const int* in_sizes, int n_in,
                              void* d_out, int out_size, void* d_ws, size_t ws_size,
                              hipStream_t stream) {
    const float* hidden = (const float*)d_in[0];
    const int*   we     = (const int*)d_in[1];
    const int*   wst    = (const int*)d_in[2];
    const float* cemb   = (const float*)d_in[3];
    const float* sent   = (const float*)d_in[4];
    const float* lnw    = (const float*)d_in[5];
    const float* gw     = (const float*)d_in[6];
    const float* uw     = (const float*)d_in[7];
    const float* dw     = (const float*)d_in[8];
    const float* mlpw   = (const float*)d_in[9];
    const float* mlpb   = (const float*)d_in[10];
    const float* alpha  = (const float*)d_in[11];
    float* out = (float*)d_out;

    // workspace layout (bytes), total ~137 MB
    char* w = (char*)d_ws;
    _Float16* a16   = (_Float16*)(w);                  //  67,108,864  [M][K]
    _Float16* bt16  = (_Float16*)(w + 67108864);       //  33,554,432  [N][K]
    float*    bvec  = (float*)(w + 100663296);         //   4,194,304
    float*    ent   = (float*)(w + 104857600);         //     512,000
    float*    h1    = (float*)(w + 105369600);         //  10,485,760
    float*    bdp   = (float*)(w + 115855360);         //  16,777,216  [8][256][KI]
    float*    attn  = (float*)(w + 132632576);         //     102,400
    float*    entw2 = (float*)(w + 132734976);         //   4,194,304  [256][H]
    int*      inv   = (int*)(w + 136929280);           //      32,768  [B*S]

    k_rmsnorm<<<B_ * S_, 256, 0, stream>>>(hidden, lnw, a16);
    k_wsplit<<<dim3(H_ / 64, H_ / 64), 256, 0, stream>>>(mlpw, bt16);
    k_entori<<<B_ * E_, 256, 0, stream>>>(we, cemb, sent, ent, inv);
    k_invset<<<1, 256, 0, stream>>>(wst, inv);
    k_bvec<<<B_ * E_, 256, 0, stream>>>(a16, wst, bvec);
    k_gateup<<<dim3(KI_ / 64, (B_ * E_ * 5) / 64), 256, 0, stream>>>(ent, gw, uw, h1);
    k_bd<<<dim3(KI_ / 64, (B_ * E_) / 64, 8), 256, 0, stream>>>(bvec, dw, bdp);
    k_attn<<<B_ * E_, 256, 0, stream>>>(h1, bdp, ent, we, attn);
    k_entw2<<<B_ * E_, 256, 0, stream>>>(attn, mlpw, entw2);
    k_mfma_gemm<<<(H_ / 128) * ((B_ * S_) / 128), 256, 0, stream>>>(
        a16, bt16, mlpb, hidden, alpha, entw2, inv, out);
}

// Round 8
// 966.436 us; speedup vs baseline: 1.8183x; 1.0202x over previous
//
#include <hip/hip_runtime.h>
#include <hip/hip_bf16.h>

// Problem constants (match reference)
constexpr int B_ = 4, S_ = 2048, H_ = 4096;
constexpr int E_ = 64, K_ = 4, T_ = 4;
constexpr int D_ = 100, KI_ = 2048;
constexpr float EPS_ = 1e-6f;
constexpr float NEG_ = -1e9f;

typedef _Float16 f16x8 __attribute__((ext_vector_type(8)));
typedef _Float16 f16x4 __attribute__((ext_vector_type(4)));
typedef float    f32x4 __attribute__((ext_vector_type(4)));

// global_load_lds: LDS dest is wave-uniform base + lane*16 (linear); global
// source address is per-lane. Size must be the literal 16.
#define GLL(gp, ldsbyte)                                                        \
    __builtin_amdgcn_global_load_lds(                                           \
        (__attribute__((address_space(1))) void*)(uintptr_t)(gp),               \
        (__attribute__((address_space(3))) void*)(uintptr_t)(smem_raw + (ldsbyte)), \
        16, 0, 0)

// ---------------------------------------------------------------------------
// K1: RMSNorm -> fp16   a16 = fp16(w * x * rsqrt(mean(x^2)+eps))
// ---------------------------------------------------------------------------
__global__ __launch_bounds__(256) void k_rmsnorm(const float* __restrict__ x,
                                                 const float* __restrict__ w,
                                                 _Float16* __restrict__ a16) {
    const int row = blockIdx.x;
    const int t = threadIdx.x;
    const float4* xr = reinterpret_cast<const float4*>(x + (size_t)row * H_);
    const float4* wr = reinterpret_cast<const float4*>(w);

    float4 v[4];
    float ss = 0.f;
#pragma unroll
    for (int i = 0; i < 4; ++i) {
        v[i] = xr[t + 256 * i];
        ss += v[i].x * v[i].x + v[i].y * v[i].y + v[i].z * v[i].z + v[i].w * v[i].w;
    }
    __shared__ float red[4];
#pragma unroll
    for (int off = 32; off; off >>= 1) ss += __shfl_down(ss, off);
    if ((t & 63) == 0) red[t >> 6] = ss;
    __syncthreads();
    if (t == 0) {
        float s = red[0] + red[1] + red[2] + red[3];
        red[0] = rsqrtf(s / (float)H_ + EPS_);
    }
    __syncthreads();
    const float scale = red[0];
#pragma unroll
    for (int i = 0; i < 4; ++i) {
        float4 wv = wr[t + 256 * i];
        f16x4 hv;
        hv[0] = (_Float16)(v[i].x * scale * wv.x);
        hv[1] = (_Float16)(v[i].y * scale * wv.y);
        hv[2] = (_Float16)(v[i].z * scale * wv.z);
        hv[3] = (_Float16)(v[i].w * scale * wv.w);
        *reinterpret_cast<f16x4*>(a16 + (size_t)row * H_ + 4 * (t + 256 * i)) = hv;
    }
}

// ---------------------------------------------------------------------------
// K2: transpose W1 = mlp_w[0:H,:]  ->  bt16 [N=H][K=H] fp16 (B^T for GEMM)
// ---------------------------------------------------------------------------
__global__ __launch_bounds__(256) void k_wsplit(const float* __restrict__ w1,
                                                _Float16* __restrict__ bt16) {
    __shared__ float sT[64][68];
    const int k0 = blockIdx.x * 64;
    const int n0 = blockIdx.y * 64;
    const int t = threadIdx.x;

#pragma unroll
    for (int q = 0; q < 4; ++q) {
        const int r = (t >> 4) + q * 16;
        const int c = (t & 15) * 4;
        float4 v = *reinterpret_cast<const float4*>(&w1[(size_t)(k0 + r) * H_ + n0 + c]);
        *reinterpret_cast<float4*>(&sT[r][c]) = v;
    }
    __syncthreads();
#pragma unroll
    for (int p = 0; p < 2; ++p) {
        const int n = (t >> 3) + p * 32;
        const int kc = (t & 7) * 8;
        f16x8 hv;
#pragma unroll
        for (int j = 0; j < 8; ++j) hv[j] = (_Float16)sT[kc + j][n];
        *reinterpret_cast<f16x8*>(bt16 + (size_t)(n0 + n) * H_ + k0 + kc) = hv;
    }
}

// ---------------------------------------------------------------------------
// K3: gather concept embeddings + sentinel; also init inv map to -1
// ---------------------------------------------------------------------------
__global__ __launch_bounds__(256) void k_entori(const int* __restrict__ we,
                                                const float* __restrict__ cemb,
                                                const float* __restrict__ sent,
                                                float* __restrict__ ent,
                                                int* __restrict__ inv) {
    const int be = blockIdx.x;
    const int t = threadIdx.x;
    if (t < 32) inv[be * 32 + t] = -1;     // B*S = 256*32
    for (int idx = t; idx < 5 * D_; idx += 256) {
        const int k = idx / D_, d = idx % D_;
        float v;
        if (k < K_) {
            int c = we[be * K_ + k];
            if (c < 0) c = 0;
            v = cemb[(size_t)c * D_ + d];
        } else {
            v = sent[d];
        }
        ent[(size_t)be * (5 * D_) + idx] = v;
    }
}

// K3b: inv[b*S + pos] = be for each subtoken position (positions unique/sample)
__global__ __launch_bounds__(256) void k_invset(const int* __restrict__ wst,
                                                int* __restrict__ inv) {
    const int be = threadIdx.x;
    if (be < B_ * E_) {
        const int b = be / E_;
#pragma unroll
        for (int j = 0; j < T_; ++j) {
            int p = wst[be * T_ + j];
            if (p >= 0 && p < S_) inv[b * S_ + p] = be;
        }
    }
}

// ---------------------------------------------------------------------------
// K4: per-entity mean of gathered subtoken hidden states (fp16 -> f32 acc)
// ---------------------------------------------------------------------------
__global__ __launch_bounds__(256) void k_bvec(const _Float16* __restrict__ a16,
                                              const int* __restrict__ wst,
                                              float* __restrict__ bvec) {
    const int be = blockIdx.x;
    const int b = be / E_;
    const int t = threadIdx.x;

    int pos[T_];
    int cnt = 0;
#pragma unroll
    for (int j = 0; j < T_; ++j) {
        int p = wst[be * T_ + j];
        if (p >= 0) cnt++; else p = -1;
        pos[j] = p;
    }
    const float inv = 1.f / (float)(cnt > 0 ? cnt : 1);

    float acc[16] = {};
#pragma unroll
    for (int j = 0; j < T_; ++j) {
        if (pos[j] >= 0) {
            const f16x8* rh = reinterpret_cast<const f16x8*>(
                a16 + ((size_t)b * S_ + pos[j]) * H_ + t * 16);
#pragma unroll
            for (int c2 = 0; c2 < 2; ++c2) {
                f16x8 h = rh[c2];
#pragma unroll
                for (int e = 0; e < 8; ++e) acc[c2 * 8 + e] += (float)h[e];
            }
        }
    }
    float4* dst = reinterpret_cast<float4*>(bvec + (size_t)be * H_ + t * 16);
#pragma unroll
    for (int c = 0; c < 4; ++c) {
        float4 r = {acc[4 * c] * inv, acc[4 * c + 1] * inv,
                    acc[4 * c + 2] * inv, acc[4 * c + 3] * inv};
        dst[c] = r;
    }
}

// ---------------------------------------------------------------------------
// K5: h1 = silu(ent @ gate_w) * (ent @ up_w)   [1280, KI], K=D=100 (f32 VALU)
//     micro-tile cols strided (tx + 16j): sG reads conflict-free
// ---------------------------------------------------------------------------
__global__ __launch_bounds__(256) void k_gateup(const float* __restrict__ ent,
                                                const float* __restrict__ gw,
                                                const float* __restrict__ uw,
                                                float* __restrict__ h1) {
    __shared__ float sA[64][D_];
    __shared__ float sG[D_][64];
    const int n0 = blockIdx.x * 64;
    const int m0 = blockIdx.y * 64;
    const int t = threadIdx.x;
    const int tx = t & 15, ty = t >> 4;

    for (int idx = t; idx < 64 * D_; idx += 256) {
        int m = idx / D_, d = idx % D_;
        sA[m][d] = ent[(size_t)(m0 + m) * D_ + d];
    }
    for (int idx = t; idx < D_ * 64; idx += 256) {
        int d = idx / 64, n = idx % 64;
        sG[d][n] = gw[(size_t)d * KI_ + n0 + n];
    }
    __syncthreads();

    float g[4][4] = {}, u[4][4] = {};
    for (int d = 0; d < D_; ++d) {
        float a[4], bg[4], bub[4];
#pragma unroll
        for (int i = 0; i < 4; ++i) a[i] = sA[ty * 4 + i][d];
#pragma unroll
        for (int j = 0; j < 4; ++j) {
            bg[j] = sG[d][tx + 16 * j];
            bub[j] = uw[(size_t)d * KI_ + n0 + tx + 16 * j];
        }
#pragma unroll
        for (int i = 0; i < 4; ++i)
#pragma unroll
            for (int j = 0; j < 4; ++j) {
                g[i][j] += a[i] * bg[j];
                u[i][j] += a[i] * bub[j];
            }
    }
#pragma unroll
    for (int i = 0; i < 4; ++i)
#pragma unroll
        for (int j = 0; j < 4; ++j) {
            float gv = g[i][j];
            h1[(size_t)(m0 + ty * 4 + i) * KI_ + n0 + tx + 16 * j] =
                (gv / (1.f + expf(-gv))) * u[i][j];
        }
}

// ---------------------------------------------------------------------------
// K6: split-K bd partials: bdp[z][m][ki] = sum_{h in chunk z} bvec[m,h]*dw[ki,h]
//     micro-tile cols strided (tx + 16j): sB reads 2-way (free)
// ---------------------------------------------------------------------------
__global__ __launch_bounds__(256) void k_bd(const float* __restrict__ bvec,
                                            const float* __restrict__ dw,
                                            float* __restrict__ bdp) {
    __shared__ float sA[64][20];
    __shared__ float sB[64][20];
    const int n0 = blockIdx.x * 64;
    const int m0 = blockIdx.y * 64;
    const int z = blockIdx.z;
    const int t = threadIdx.x;
    const int tx = t & 15, ty = t >> 4;
    const int lr = t >> 2, lc = (t & 3) * 4;

    float acc[4][4] = {};
    for (int k0 = z * 512; k0 < (z + 1) * 512; k0 += 16) {
        *reinterpret_cast<float4*>(&sA[lr][lc]) =
            *reinterpret_cast<const float4*>(&bvec[(size_t)(m0 + lr) * H_ + k0 + lc]);
        *reinterpret_cast<float4*>(&sB[lr][lc]) =
            *reinterpret_cast<const float4*>(&dw[(size_t)(n0 + lr) * H_ + k0 + lc]);
        __syncthreads();
#pragma unroll
        for (int kk = 0; kk < 16; ++kk) {
            float a[4], b[4];
#pragma unroll
            for (int i = 0; i < 4; ++i) a[i] = sA[ty * 4 + i][kk];
#pragma unroll
            for (int j = 0; j < 4; ++j) b[j] = sB[tx + 16 * j][kk];
#pragma unroll
            for (int i = 0; i < 4; ++i)
#pragma unroll
                for (int j = 0; j < 4; ++j) acc[i][j] += a[i] * b[j];
        }
        __syncthreads();
    }
#pragma unroll
    for (int i = 0; i < 4; ++i)
#pragma unroll
        for (int j = 0; j < 4; ++j)
            bdp[((size_t)z * 256 + m0 + ty * 4 + i) * KI_ + n0 + tx + 16 * j] = acc[i][j];
}

// ---------------------------------------------------------------------------
// K7: logits = h1 . (sum_z bdp) ; softmax(+mask) ; attn_out = attn @ ent_ori
// ---------------------------------------------------------------------------
__global__ __launch_bounds__(256) void k_attn(const float* __restrict__ h1,
                                              const float* __restrict__ bdp,
                                              const float* __restrict__ ent,
                                              const int* __restrict__ we,
                                              float* __restrict__ attn_out) {
    __shared__ float sbd[KI_];
    __shared__ float red[4];
    __shared__ float sl[8];
    const int be = blockIdx.x;
    const int t = threadIdx.x;

    for (int i = t; i < KI_; i += 256) {
        float s = 0.f;
#pragma unroll
        for (int z = 0; z < 8; ++z) s += bdp[((size_t)z * 256 + be) * KI_ + i];
        sbd[i] = s;
    }
    __syncthreads();

    for (int k = 0; k < 5; ++k) {
        const float* hrow = h1 + ((size_t)be * 5 + k) * KI_;
        float s = 0.f;
        for (int i = t; i < KI_; i += 256) s += hrow[i] * sbd[i];
#pragma unroll
        for (int off = 32; off; off >>= 1) s += __shfl_down(s, off);
        if ((t & 63) == 0) red[t >> 6] = s;
        __syncthreads();
        if (t == 0) sl[k] = red[0] + red[1] + red[2] + red[3];
        __syncthreads();
    }
    if (t == 0) {
        float lg[5];
#pragma unroll
        for (int k = 0; k < K_; ++k)
            lg[k] = sl[k] + (we[be * K_ + k] == -1 ? NEG_ : 0.f);
        lg[4] = sl[4];
        float mx = lg[0];
#pragma unroll
        for (int k = 1; k < 5; ++k) mx = fmaxf(mx, lg[k]);
        float sum = 0.f;
#pragma unroll
        for (int k = 0; k < 5; ++k) { lg[k] = expf(lg[k] - mx); sum += lg[k]; }
        float is = 1.f / sum;
#pragma unroll
        for (int k = 0; k < 5; ++k) sl[k] = lg[k] * is;
    }
    __syncthreads();
    if (t < D_) {
        float a = 0.f;
#pragma unroll
        for (int k = 0; k < 5; ++k) a += sl[k] * ent[((size_t)be * 5 + k) * D_ + t];
        attn_out[(size_t)be * D_ + t] = a;
    }
}

// ---------------------------------------------------------------------------
// K8: entw2[be][h] = attn_out[be] @ W2   (W2 = mlp_w[H:,:], D x H)
// ---------------------------------------------------------------------------
__global__ __launch_bounds__(256) void k_entw2(const float* __restrict__ attn_out,
                                               const float* __restrict__ mlpw,
                                               float* __restrict__ entw2) {
    __shared__ float sa[D_];
    const int be = blockIdx.x;
    const int t = threadIdx.x;
    if (t < D_) sa[t] = attn_out[(size_t)be * D_ + t];
    __syncthreads();

    const float* W2 = mlpw + (size_t)H_ * H_;
#pragma unroll
    for (int i = 0; i < 4; ++i) {
        const int h4 = t + 256 * i;          // float4 column index
        float4 c = make_float4(0.f, 0.f, 0.f, 0.f);
        for (int d = 0; d < D_; ++d) {
            float4 w = *reinterpret_cast<const float4*>(&W2[(size_t)d * H_ + 4 * h4]);
            float av = sa[d];
            c.x += av * w.x; c.y += av * w.y; c.z += av * w.z; c.w += av * w.w;
        }
        *reinterpret_cast<float4*>(&entw2[(size_t)be * H_ + 4 * h4]) = c;
    }
}

// ---------------------------------------------------------------------------
// K9: main GEMM  out = silu(A@W1^T + bias + entw2[inv]) * alpha + resid
//     K-loop: round-5 verified m97 structure (128x128, BK=32, 16KB LDS,
//     4 waves 2x2, 16x16x32_f16, global_load_lds, 2-barrier). No swizzle
//     (T2 null at 2-phase — measured round 7).
//     Epilogue: 4-chunk LDS transpose (reuse smem as [32][129] f32) ->
//     fully-coalesced float4 resid/entw2/bias/out (was 64 scalar RMW/thread).
// ---------------------------------------------------------------------------
__global__ __launch_bounds__(256) void k_mfma_gemm(const _Float16* __restrict__ A,
                                                   const _Float16* __restrict__ Bt,
                                                   const float* __restrict__ bias,
                                                   const float* __restrict__ resid,
                                                   const float* __restrict__ alphap,
                                                   const float* __restrict__ entw2,
                                                   const int* __restrict__ inv,
                                                   float* __restrict__ Out) {
    // 16512 B: loop uses first 16384 (A tile @0, B tile @8192);
    // epilogue reuses as [32][129] f32 (16512 B)
    __shared__ __align__(16) char smem_raw[16512];
    _Float16* smem = reinterpret_cast<_Float16*>(smem_raw);
    const int t = threadIdx.x;
    const int lane = t & 63, wid = t >> 6;
    const int wr = wid >> 1, wc = wid & 1;

    // XCD-aware bijective swizzle (nwg = 2048, divisible by 8)
    const int bid = blockIdx.x;
    const int swz = (bid & 7) * 256 + (bid >> 3);
    const int mb = swz >> 5, nb = swz & 31;
    const size_t m0 = (size_t)mb * 128, n0 = (size_t)nb * 128;

    // staging: chunk c -> row = c>>2, k-elem = (c&3)*8 (16B = 8 fp16)
    const int c0 = wid * 128 + lane, c1 = c0 + 64;
    const size_t offA0 = ((size_t)(m0 + (c0 >> 2))) * H_ + (c0 & 3) * 8;
    const size_t offA1 = ((size_t)(m0 + (c1 >> 2))) * H_ + (c1 & 3) * 8;
    const size_t offB0 = ((size_t)(n0 + (c0 >> 2))) * H_ + (c0 & 3) * 8;
    const size_t offB1 = ((size_t)(n0 + (c1 >> 2))) * H_ + (c1 & 3) * 8;
    const unsigned ldsW = wid * 2048;       // bytes, wave region within a tile

    const int fr = lane & 15;               // fragment row within 16-group
    const int kq = (lane >> 4) * 8;         // fragment k-offset (elements)

    f32x4 acc[4][4] = {};

    for (int k0 = 0; k0 < H_; k0 += 32) {
        GLL(A + offA0 + k0, ldsW);
        GLL(A + offA1 + k0, ldsW + 1024);
        GLL(Bt + offB0 + k0, 8192 + ldsW);          // B tile base = byte 8192
        GLL(Bt + offB1 + k0, 8192 + ldsW + 1024);
        __syncthreads();    // compiler drains vmcnt(0) before s_barrier

        f16x8 af[4], bf[4];
#pragma unroll
        for (int i = 0; i < 4; ++i) {
            af[i] = *reinterpret_cast<const f16x8*>(smem + (wr * 64 + i * 16 + fr) * 32 + kq);
            bf[i] = *reinterpret_cast<const f16x8*>(smem + 4096 + (wc * 64 + i * 16 + fr) * 32 + kq);
        }
#pragma unroll
        for (int i = 0; i < 4; ++i)
#pragma unroll
            for (int j = 0; j < 4; ++j)
                acc[i][j] = __builtin_amdgcn_mfma_f32_16x16x32_f16(af[i], bf[j], acc[i][j], 0, 0, 0);
        __syncthreads();
    }

    // ---- epilogue: 4 chunks of 32 rows; LDS transpose -> coalesced I/O ----
    float* sfp = reinterpret_cast<float*>(smem_raw);   // [32][129]
    const float alpha = alphap[0];
    const int cr = (lane >> 4) * 4;
    const int cc = lane & 15;
    const int col4 = (t & 31) * 4;          // this thread's 4-col group
    const int rbase = t >> 5;               // row 0..7, +8q below

#pragma unroll
    for (int c = 0; c < 4; ++c) {
        if (c) __syncthreads();             // prior chunk's reads done
        if (wr == (c >> 1)) {
            const int i0 = (c & 1) * 2;
#pragma unroll
            for (int ii = 0; ii < 2; ++ii) {
#pragma unroll
                for (int j = 0; j < 4; ++j) {
                    const int lr = ii * 16 + cr;
                    const int lc = wc * 64 + j * 16 + cc;
#pragma unroll
                    for (int r = 0; r < 4; ++r)
                        sfp[(lr + r) * 129 + lc] = acc[i0 + ii][j][r];
                }
            }
        }
        __syncthreads();
#pragma unroll
        for (int q = 0; q < 4; ++q) {
            const int lrow = rbase + 8 * q;
            const int grow = (int)m0 + c * 32 + lrow;
            f32x4 v = *reinterpret_cast<const f32x4*>(&sfp[lrow * 129 + col4]);
            const float4 bv = *reinterpret_cast<const float4*>(&bias[n0 + col4]);
            v[0] += bv.x; v[1] += bv.y; v[2] += bv.z; v[3] += bv.w;
            const int be = inv[grow];
            if (be >= 0) {
                const float4 ev = *reinterpret_cast<const float4*>(
                    &entw2[(size_t)be * H_ + n0 + col4]);
                v[0] += ev.x; v[1] += ev.y; v[2] += ev.z; v[3] += ev.w;
            }
            const size_t o = (size_t)grow * H_ + n0 + col4;
            const float4 rv = *reinterpret_cast<const float4*>(&resid[o]);
            float4 ov;
            ov.x = (v[0] / (1.f + expf(-v[0]))) * alpha + rv.x;
            ov.y = (v[1] / (1.f + expf(-v[1]))) * alpha + rv.y;
            ov.z = (v[2] / (1.f + expf(-v[2]))) * alpha + rv.z;
            ov.w = (v[3] / (1.f + expf(-v[3]))) * alpha + rv.w;
            *reinterpret_cast<float4*>(&Out[o]) = ov;
        }
    }
}

// ---------------------------------------------------------------------------
extern "C" void kernel_launch(void* const* d_in, const int* in_sizes, int n_in,
                              void* d_out, int out_size, void* d_ws, size_t ws_size,
                              hipStream_t stream) {
    const float* hidden = (const float*)d_in[0];
    const int*   we     = (const int*)d_in[1];
    const int*   wst    = (const int*)d_in[2];
    const float* cemb   = (const float*)d_in[3];
    const float* sent   = (const float*)d_in[4];
    const float* lnw    = (const float*)d_in[5];
    const float* gw     = (const float*)d_in[6];
    const float* uw     = (const float*)d_in[7];
    const float* dw     = (const float*)d_in[8];
    const float* mlpw   = (const float*)d_in[9];
    const float* mlpb   = (const float*)d_in[10];
    const float* alpha  = (const float*)d_in[11];
    float* out = (float*)d_out;

    // workspace layout (bytes), total ~137 MB
    char* w = (char*)d_ws;
    _Float16* a16   = (_Float16*)(w);                  //  67,108,864  [M][K]
    _Float16* bt16  = (_Float16*)(w + 67108864);       //  33,554,432  [N][K]
    float*    bvec  = (float*)(w + 100663296);         //   4,194,304
    float*    ent   = (float*)(w + 104857600);         //     512,000
    float*    h1    = (float*)(w + 105369600);         //  10,485,760
    float*    bdp   = (float*)(w + 115855360);         //  16,777,216  [8][256][KI]
    float*    attn  = (float*)(w + 132632576);         //     102,400
    float*    entw2 = (float*)(w + 132734976);         //   4,194,304  [256][H]
    int*      inv   = (int*)(w + 136929280);           //      32,768  [B*S]

    k_rmsnorm<<<B_ * S_, 256, 0, stream>>>(hidden, lnw, a16);
    k_wsplit<<<dim3(H_ / 64, H_ / 64), 256, 0, stream>>>(mlpw, bt16);
    k_entori<<<B_ * E_, 256, 0, stream>>>(we, cemb, sent, ent, inv);
    k_invset<<<1, 256, 0, stream>>>(wst, inv);
    k_bvec<<<B_ * E_, 256, 0, stream>>>(a16, wst, bvec);
    k_gateup<<<dim3(KI_ / 64, (B_ * E_ * 5) / 64), 256, 0, stream>>>(ent, gw, uw, h1);
    k_bd<<<dim3(KI_ / 64, (B_ * E_) / 64, 8), 256, 0, stream>>>(bvec, dw, bdp);
    k_attn<<<B_ * E_, 256, 0, stream>>>(h1, bdp, ent, we, attn);
    k_entw2<<<B_ * E_, 256, 0, stream>>>(attn, mlpw, entw2);
    k_mfma_gemm<<<(H_ / 128) * ((B_ * S_) / 128), 256, 0, stream>>>(
        a16, bt16, mlpb, hidden, alpha, entw2, inv, out);
}